// Round 15
// baseline (147.675 us; speedup 1.0000x reference)
//
#include <hip/hip_runtime.h>
#include <hip/hip_bf16.h>
#include <stdint.h>

// Problem constants: B=4, S=2048, D=768, H=12, HD=64
// M = B*S = 8192, N1 = 3*D = 2304, BH = 48

typedef __attribute__((ext_vector_type(8))) short bf16x8;
typedef __attribute__((ext_vector_type(4))) float f32x4;
typedef __attribute__((ext_vector_type(4))) unsigned short u16x4;

__device__ __forceinline__ unsigned short f2bf(float x) {
  union { float f; uint32_t u; } v; v.f = x;
  uint32_t r = v.u + 0x7FFF + ((v.u >> 16) & 1);
  return (unsigned short)(r >> 16);
}

__device__ __forceinline__ uint32_t cvtpk_bf16(float lo, float hi) {
  uint32_t r;
  asm("v_cvt_pk_bf16_f32 %0, %1, %2" : "=v"(r) : "v"(lo), "v"(hi));
  return r;  // low16 = bf16(lo), high16 = bf16(hi)  [HW-verified by R3 pass]
}

__device__ __forceinline__ void gload_lds16(const void* g, void* l) {
  __builtin_amdgcn_global_load_lds(
      (const __attribute__((address_space(1))) void*)g,
      (__attribute__((address_space(3))) void*)l, 16, 0, 0);
}

// ---------------- fused prep: x cast + both weight transposes, one launch ----
// blocks [0,6144): cast x (f32->bf16, 4 elem/thread)
// blocks [6144,6576): transpose+cast w_qkv (768x2304) 64x64 tiles
// blocks [6576,6720): transpose+cast w_proj (768x768)
__device__ __forceinline__ void transpose_tile(const float* __restrict__ W,
                                               unsigned short* __restrict__ Wt,
                                               int K, int N, int k0, int n0,
                                               float (*tile)[65], int t) {
#pragma unroll
  for (int i = 0; i < 16; i++) {
    int idx = i * 256 + t; int r = idx >> 6, c = idx & 63;
    tile[r][c] = W[(size_t)(k0 + r) * N + n0 + c];
  }
  __syncthreads();
#pragma unroll
  for (int i = 0; i < 16; i++) {
    int idx = i * 256 + t; int r = idx >> 6, c = idx & 63;
    Wt[(size_t)(n0 + r) * K + k0 + c] = f2bf(tile[c][r]);
  }
}

__global__ void prep_kernel(const float* __restrict__ x,
                            unsigned short* __restrict__ xb,
                            const float* __restrict__ w_qkv,
                            unsigned short* __restrict__ wqt,
                            const float* __restrict__ w_proj,
                            unsigned short* __restrict__ wpt) {
  __shared__ float tile[64][65];
  const int id = blockIdx.x, t = threadIdx.x;
  if (id < 6144) {
    int idx = (id * 256 + t) * 4;
    f32x4 v = *(const f32x4*)(x + idx);
    u16x4 o;
    o[0] = f2bf(v[0]); o[1] = f2bf(v[1]); o[2] = f2bf(v[2]); o[3] = f2bf(v[3]);
    *(u16x4*)(xb + idx) = o;
  } else if (id < 6576) {
    int tid = id - 6144;
    transpose_tile(w_qkv, wqt, 768, 2304, (tid / 36) * 64, (tid % 36) * 64,
                   tile, t);
  } else {
    int tid = id - 6576;
    transpose_tile(w_proj, wpt, 768, 768, (tid / 12) * 64, (tid % 12) * 64,
                   tile, t);
  }
}

// ---------------- GEMM: C[M][N] = A[M][K] * Bt[N][K]^T + bias ----------------
// Both epilogues: bf16 A via global_load_lds DMA (R12/R13: f32 reg-staging
// regressed). Both use 1D grids with XCD-residency mapping (id%8 = XCD,
// HW-confirmed R9/R13): all n-blocks of an m-panel on one XCD.
// EPI 0: grid 1152 (18 n-blocks/panel). Epilogue -> Q (0.125*log2e)
//        [bh][s][64], K [bh][s][64], V^T [bh][64][s_permuted];
//        s'=(s&~31)+((s>>2)&3)*8+((s>>4)&1)*4 (PV b128 frag).
// EPI 1: grid 384 (6 n-blocks/panel); out f32 row-major [M][N].
template <int EPI>
__global__ __launch_bounds__(256, 2) void gemm_kernel(
    const unsigned short* __restrict__ A,
    const unsigned short* __restrict__ Bt,
    const float* __restrict__ bias,
    void* __restrict__ out0,
    unsigned short* __restrict__ Kb,
    unsigned short* __restrict__ Vt,
    int M, int N, int K) {
  __shared__ unsigned short As[128 * 64];
  __shared__ unsigned short Bs[128 * 64];
  const int tid = threadIdx.x;
  const int wave = tid >> 6, lane = tid & 63;
  const int wm = wave >> 1, wn = wave & 1;
  const int id = blockIdx.x;
  const int xcd = id & 7, slot = id >> 3;
  int m0, n0;
  if (EPI == 0) {
    m0 = (xcd * 8 + slot / 18) * 128;
    n0 = (slot % 18) * 128;
  } else {
    m0 = (xcd * 8 + slot / 6) * 128;
    n0 = (slot % 6) * 128;
  }
  const int g = lane >> 4, c16 = lane & 15;
  f32x4 acc[4][4] = {};

  for (int k0 = 0; k0 < K; k0 += 64) {
    int rb = wave * 32;
#pragma unroll
    for (int j = 0; j < 4; j++) {
      int r = rb + j * 8 + (lane >> 3);
      int ca = (lane & 7) ^ (r & 7);
      gload_lds16(A + (size_t)(m0 + r) * K + k0 + ca * 8, As + (rb + j * 8) * 64);
      gload_lds16(Bt + (size_t)(n0 + r) * K + k0 + ca * 8, Bs + (rb + j * 8) * 64);
    }
    __syncthreads();
#pragma unroll
    for (int ks = 0; ks < 2; ks++) {
      bf16x8 af[4], bfr[4];
#pragma unroll
      for (int mi = 0; mi < 4; mi++) {
        int row = wm * 64 + mi * 16 + c16;
        int ch = (ks * 4 + g) ^ (row & 7);
        af[mi] = *(const bf16x8*)(As + row * 64 + ch * 8);
      }
#pragma unroll
      for (int nj = 0; nj < 4; nj++) {
        int row = wn * 64 + nj * 16 + c16;
        int ch = (ks * 4 + g) ^ (row & 7);
        bfr[nj] = *(const bf16x8*)(Bs + row * 64 + ch * 8);
      }
#pragma unroll
      for (int mi = 0; mi < 4; mi++)
#pragma unroll
        for (int nj = 0; nj < 4; nj++)
          acc[mi][nj] = __builtin_amdgcn_mfma_f32_16x16x32_bf16(
              af[mi], bfr[nj], acc[mi][nj], 0, 0, 0);
    }
    __syncthreads();
  }

  // epilogue. D layout: col = lane&15, row = (lane>>4)*4 + reg
  if (EPI == 0) {
    const float QSC = 0.125f * 1.44269504088896f;  // fold log2(e) for exp2 softmax
    unsigned short* Qb = (unsigned short*)out0;
#pragma unroll
    for (int nj = 0; nj < 4; nj++) {
      int n = n0 + wn * 64 + nj * 16 + c16;
      int t = n / 768, rr = n % 768;
      int h = rr >> 6, d = rr & 63;
      float bv = bias[n];
#pragma unroll
      for (int mi = 0; mi < 4; mi++) {
        int mrow = m0 + wm * 64 + mi * 16 + g * 4;
        int b = mrow >> 11, s = mrow & 2047;
        if (t == 0) {
          size_t base = ((size_t)(b * 12 + h) * 2048 + s) * 64 + d;
#pragma unroll
          for (int rg = 0; rg < 4; rg++)
            Qb[base + (size_t)rg * 64] = f2bf((acc[mi][nj][rg] + bv) * QSC);
        } else if (t == 1) {
          size_t base = ((size_t)(b * 12 + h) * 2048 + s) * 64 + d;
#pragma unroll
          for (int rg = 0; rg < 4; rg++)
            Kb[base + (size_t)rg * 64] = f2bf(acc[mi][nj][rg] + bv);
        } else {
          // V store with key-permutation (4-aligned groups stay contiguous)
          int sp = (s & ~31) + (((s >> 2) & 3) << 3) + (((s >> 4) & 1) << 2);
          u16x4 p;
          p[0] = f2bf(acc[mi][nj][0] + bv);
          p[1] = f2bf(acc[mi][nj][1] + bv);
          p[2] = f2bf(acc[mi][nj][2] + bv);
          p[3] = f2bf(acc[mi][nj][3] + bv);
          *(u16x4*)(Vt + ((size_t)(b * 12 + h) * 64 + d) * 2048 + sp) = p;
        }
      }
    }
  } else {
    float* outp = (float*)out0;
#pragma unroll
    for (int nj = 0; nj < 4; nj++) {
      int n = n0 + wn * 64 + nj * 16 + c16;
      float bv = bias[n];
#pragma unroll
      for (int mi = 0; mi < 4; mi++) {
        int mrow = m0 + wm * 64 + mi * 16 + g * 4;
#pragma unroll
        for (int rg = 0; rg < 4; rg++)
          outp[(size_t)(mrow + rg) * N + n] = acc[mi][nj][rg] + bv;
      }
    }
  }
}

// ---------------- flash attention v12: v10 math + 2 KV-tiles per barrier pair --
// grid 768 x 256 (4 waves, 2 q-subtiles of 16 rows each). Identical per-tile
// math to v10 (63.2 us verified; bit-identical order), but K/V for TWO tiles
// are staged together into statically-indexed double LDS arrays, halving the
// barrier-drain count (64 -> 32). XCD-residency swizzle, in-register P with
// permuted-Vt b128 B-frags, exp2-no-max softmax, deferred l-reduction.
__global__ __launch_bounds__(256, 4) void attn_kernel(
    const unsigned short* __restrict__ Qb,
    const unsigned short* __restrict__ Kb,
    const unsigned short* __restrict__ Vt,
    unsigned short* __restrict__ Ao) {
  __shared__ unsigned short Ks[2][64 * 64];
  __shared__ unsigned short Vs[2][64 * 64];
  const int id = blockIdx.x;
  const int xcd = id & 7, slot = id >> 3;
  const int bh = xcd * 6 + (slot % 6);
  const int q0 = (slot / 6) * 128;
  const int tid = threadIdx.x;
  const int wave = tid >> 6, lane = tid & 63;
  const int g = lane >> 4, c16 = lane & 15;
  const int rw = c16 & 7;
  const int rb = wave * 16;

  // staging geometry (kt-invariant): rows sr, sr+8 share the same chunk swizzle
  const int sr = rb + (lane >> 3);
  const int sca = (lane & 7) ^ (sr & 7);
  const unsigned short* kp = Kb + ((size_t)bh * 2048 + sr) * 64 + sca * 8;
  const unsigned short* vp = Vt + ((size_t)bh * 64 + sr) * 2048 + sca * 8;

  // Q fragments: subtile qa rows q0+wave*32+qa*16+c16, k-chunks ks*32+g*8
  bf16x8 qf[2][2];
  {
    const unsigned short* qp =
        Qb + ((size_t)bh * 2048 + q0 + wave * 32 + c16) * 64;
#pragma unroll
    for (int qa = 0; qa < 2; qa++) {
      qf[qa][0] = *(const bf16x8*)(qp + qa * 1024 + g * 8);
      qf[qa][1] = *(const bf16x8*)(qp + qa * 1024 + 32 + g * 8);
    }
  }
  f32x4 acc_o[2][4] = {};
  float l_run[2] = {0.f, 0.f};  // lane-partial until final reduce
  const int alane = (lane & 48) + g * 4;  // src lane base for l shfl

  for (int kt2 = 0; kt2 < 16; kt2++) {
    // stage keys [kt2*128, kt2*128+128) : two 64-key tiles, one drain
#pragma unroll
    for (int bufi = 0; bufi < 2; bufi++) {
      const unsigned short* kpb = kp + bufi * 64 * 64;
      const unsigned short* vpb = vp + bufi * 64;
      gload_lds16(kpb, &Ks[bufi][rb * 64]);
      gload_lds16(kpb + 8 * 64, &Ks[bufi][(rb + 8) * 64]);
      gload_lds16(vpb, &Vs[bufi][rb * 64]);
      gload_lds16(vpb + 8 * 2048, &Vs[bufi][(rb + 8) * 64]);
    }
    kp += 2 * 64 * 64;
    vp += 128;
    __syncthreads();

#pragma unroll
    for (int bufi = 0; bufi < 2; bufi++) {
      // S^T = K * Q^T ; K-frags shared by both q-subtiles
      f32x4 sacc[2][4] = {};
#pragma unroll
      for (int ks = 0; ks < 2; ks++) {
#pragma unroll
        for (int nf = 0; nf < 4; nf++) {
          int row = nf * 16 + c16;
          int ch = (ks * 4 + g) ^ (row & 7);
          bf16x8 kf = *(const bf16x8*)(&Ks[bufi][row * 64 + ch * 8]);
          sacc[0][nf] = __builtin_amdgcn_mfma_f32_16x16x32_bf16(
              kf, qf[0][ks], sacc[0][nf], 0, 0, 0);
          sacc[1][nf] = __builtin_amdgcn_mfma_f32_16x16x32_bf16(
              kf, qf[1][ks], sacc[1][nf], 0, 0, 0);
        }
      }

      // exp2 softmax (no max), in place; lane-partial row-sum (reduce later)
#pragma unroll
      for (int qa = 0; qa < 2; qa++) {
        float rs = 0.f;
#pragma unroll
        for (int nf = 0; nf < 4; nf++) {
          sacc[qa][nf][0] = __builtin_amdgcn_exp2f(sacc[qa][nf][0]);
          sacc[qa][nf][1] = __builtin_amdgcn_exp2f(sacc[qa][nf][1]);
          sacc[qa][nf][2] = __builtin_amdgcn_exp2f(sacc[qa][nf][2]);
          sacc[qa][nf][3] = __builtin_amdgcn_exp2f(sacc[qa][nf][3]);
          rs += (sacc[qa][nf][0] + sacc[qa][nf][1]) +
                (sacc[qa][nf][2] + sacc[qa][nf][3]);
        }
        l_run[qa] += rs;
      }

      // O += P * V : A-frag in-register (v8 slot order), B-frag single b128
#pragma unroll
      for (int ks = 0; ks < 2; ks++) {
        union { uint32_t w[4]; bf16x8 v8; } pa0, pa1;
        pa0.w[0] = cvtpk_bf16(sacc[0][2 * ks][0], sacc[0][2 * ks][1]);
        pa0.w[1] = cvtpk_bf16(sacc[0][2 * ks][2], sacc[0][2 * ks][3]);
        pa0.w[2] = cvtpk_bf16(sacc[0][2 * ks + 1][0], sacc[0][2 * ks + 1][1]);
        pa0.w[3] = cvtpk_bf16(sacc[0][2 * ks + 1][2], sacc[0][2 * ks + 1][3]);
        pa1.w[0] = cvtpk_bf16(sacc[1][2 * ks][0], sacc[1][2 * ks][1]);
        pa1.w[1] = cvtpk_bf16(sacc[1][2 * ks][2], sacc[1][2 * ks][3]);
        pa1.w[2] = cvtpk_bf16(sacc[1][2 * ks + 1][0], sacc[1][2 * ks + 1][1]);
        pa1.w[3] = cvtpk_bf16(sacc[1][2 * ks + 1][2], sacc[1][2 * ks + 1][3]);
#pragma unroll
        for (int nf = 0; nf < 4; nf++) {
          int row = nf * 16 + c16;
          int ch = (ks * 4 + g) ^ rw;
          bf16x8 vf = *(const bf16x8*)(&Vs[bufi][row * 64 + ch * 8]);
          acc_o[0][nf] = __builtin_amdgcn_mfma_f32_16x16x32_bf16(
              pa0.v8, vf, acc_o[0][nf], 0, 0, 0);
          acc_o[1][nf] = __builtin_amdgcn_mfma_f32_16x16x32_bf16(
              pa1.v8, vf, acc_o[1][nf], 0, 0, 0);
        }
      }
    }
    __syncthreads();
  }

  // final l reduction, redistribute from q=c16 to rows q=g*4+rg, store
  const int b = bh / 12, h = bh % 12;
#pragma unroll
  for (int qa = 0; qa < 2; qa++) {
    float t = l_run[qa];
    t += __shfl_xor(t, 16);
    t += __shfl_xor(t, 32);
    float l_q[4];
#pragma unroll
    for (int rg = 0; rg < 4; rg++)
      l_q[rg] = __shfl(t, alane + rg);
#pragma unroll
    for (int nf = 0; nf < 4; nf++) {
#pragma unroll
      for (int rg = 0; rg < 4; rg++) {
        float v = acc_o[qa][nf][rg] / l_q[rg];
        int srow = q0 + wave * 32 + qa * 16 + g * 4 + rg;
        Ao[((size_t)(b * 2048 + srow)) * 768 + h * 64 + nf * 16 + c16] = f2bf(v);
      }
    }
  }
}

extern "C" void kernel_launch(void* const* d_in, const int* in_sizes, int n_in,
                              void* d_out, int out_size, void* d_ws, size_t ws_size,
                              hipStream_t stream) {
  const float* x      = (const float*)d_in[0];
  const float* w_qkv  = (const float*)d_in[1];
  const float* b_qkv  = (const float*)d_in[2];
  const float* w_proj = (const float*)d_in[3];
  const float* b_proj = (const float*)d_in[4];

  unsigned short* xb  = (unsigned short*)d_ws;      // 6291456 elems
  unsigned short* wqt = xb + 6291456;               // 1769472
  unsigned short* wpt = wqt + 1769472;              // 589824
  unsigned short* Qb  = wpt + 589824;               // 6291456
  unsigned short* Kb  = Qb + 6291456;               // 6291456
  unsigned short* Vt  = Kb + 6291456;               // 6291456
  unsigned short* Ao  = Vt + 6291456;               // 6291456

  prep_kernel<<<6720, 256, 0, stream>>>(x, xb, w_qkv, wqt, w_proj, wpt);

  gemm_kernel<0><<<1152, 256, 0, stream>>>(
      xb, wqt, b_qkv, (void*)Qb, Kb, Vt, 8192, 2304, 768);

  attn_kernel<<<768, 256, 0, stream>>>(Qb, Kb, Vt, Ao);

  gemm_kernel<1><<<384, 256, 0, stream>>>(
      Ao, wpt, b_proj, d_out, nullptr, nullptr, 8192, 768, 768);
}

// Round 16
// 135.340 us; speedup vs baseline: 1.0911x; 1.0911x over previous
//
#include <hip/hip_runtime.h>
#include <hip/hip_bf16.h>
#include <stdint.h>

// Problem constants: B=4, S=2048, D=768, H=12, HD=64
// M = B*S = 8192, N1 = 3*D = 2304, BH = 48

typedef __attribute__((ext_vector_type(8))) short bf16x8;
typedef __attribute__((ext_vector_type(4))) float f32x4;
typedef __attribute__((ext_vector_type(4))) unsigned short u16x4;

__device__ __forceinline__ unsigned short f2bf(float x) {
  union { float f; uint32_t u; } v; v.f = x;
  uint32_t r = v.u + 0x7FFF + ((v.u >> 16) & 1);
  return (unsigned short)(r >> 16);
}

__device__ __forceinline__ uint32_t cvtpk_bf16(float lo, float hi) {
  uint32_t r;
  asm("v_cvt_pk_bf16_f32 %0, %1, %2" : "=v"(r) : "v"(lo), "v"(hi));
  return r;  // low16 = bf16(lo), high16 = bf16(hi)  [HW-verified by R3 pass]
}

__device__ __forceinline__ void gload_lds16(const void* g, void* l) {
  __builtin_amdgcn_global_load_lds(
      (const __attribute__((address_space(1))) void*)g,
      (__attribute__((address_space(3))) void*)l, 16, 0, 0);
}

// ---------------- fused prep: x cast + both weight transposes, one launch ----
// blocks [0,6144): cast x (f32->bf16, 4 elem/thread)
// blocks [6144,6576): transpose+cast w_qkv (768x2304) 64x64 tiles
// blocks [6576,6720): transpose+cast w_proj (768x768)
__device__ __forceinline__ void transpose_tile(const float* __restrict__ W,
                                               unsigned short* __restrict__ Wt,
                                               int K, int N, int k0, int n0,
                                               float (*tile)[65], int t) {
#pragma unroll
  for (int i = 0; i < 16; i++) {
    int idx = i * 256 + t; int r = idx >> 6, c = idx & 63;
    tile[r][c] = W[(size_t)(k0 + r) * N + n0 + c];
  }
  __syncthreads();
#pragma unroll
  for (int i = 0; i < 16; i++) {
    int idx = i * 256 + t; int r = idx >> 6, c = idx & 63;
    Wt[(size_t)(n0 + r) * K + k0 + c] = f2bf(tile[c][r]);
  }
}

__global__ void prep_kernel(const float* __restrict__ x,
                            unsigned short* __restrict__ xb,
                            const float* __restrict__ w_qkv,
                            unsigned short* __restrict__ wqt,
                            const float* __restrict__ w_proj,
                            unsigned short* __restrict__ wpt) {
  __shared__ float tile[64][65];
  const int id = blockIdx.x, t = threadIdx.x;
  if (id < 6144) {
    int idx = (id * 256 + t) * 4;
    f32x4 v = *(const f32x4*)(x + idx);
    u16x4 o;
    o[0] = f2bf(v[0]); o[1] = f2bf(v[1]); o[2] = f2bf(v[2]); o[3] = f2bf(v[3]);
    *(u16x4*)(xb + idx) = o;
  } else if (id < 6576) {
    int tid = id - 6144;
    transpose_tile(w_qkv, wqt, 768, 2304, (tid / 36) * 64, (tid % 36) * 64,
                   tile, t);
  } else {
    int tid = id - 6576;
    transpose_tile(w_proj, wpt, 768, 768, (tid / 12) * 64, (tid % 12) * 64,
                   tile, t);
  }
}

// ---------------- GEMM: C[M][N] = A[M][K] * Bt[N][K]^T + bias ----------------
// Both epilogues: bf16 A via global_load_lds DMA (R12/R13: f32 reg-staging
// regressed). Both use 1D grids with XCD-residency mapping (id%8 = XCD,
// HW-confirmed R9/R13): all n-blocks of an m-panel on one XCD.
// EPI 0: grid 1152 (18 n-blocks/panel). Epilogue -> Q (0.125*log2e)
//        [bh][s][64], K [bh][s][64], V^T [bh][64][s_permuted];
//        s'=(s&~31)+((s>>2)&3)*8+((s>>4)&1)*4 (PV b128 frag).
// EPI 1: grid 384 (6 n-blocks/panel); out f32 row-major [M][N].
template <int EPI>
__global__ __launch_bounds__(256, 2) void gemm_kernel(
    const unsigned short* __restrict__ A,
    const unsigned short* __restrict__ Bt,
    const float* __restrict__ bias,
    void* __restrict__ out0,
    unsigned short* __restrict__ Kb,
    unsigned short* __restrict__ Vt,
    int M, int N, int K) {
  __shared__ unsigned short As[128 * 64];
  __shared__ unsigned short Bs[128 * 64];
  const int tid = threadIdx.x;
  const int wave = tid >> 6, lane = tid & 63;
  const int wm = wave >> 1, wn = wave & 1;
  const int id = blockIdx.x;
  const int xcd = id & 7, slot = id >> 3;
  int m0, n0;
  if (EPI == 0) {
    m0 = (xcd * 8 + slot / 18) * 128;
    n0 = (slot % 18) * 128;
  } else {
    m0 = (xcd * 8 + slot / 6) * 128;
    n0 = (slot % 6) * 128;
  }
  const int g = lane >> 4, c16 = lane & 15;
  f32x4 acc[4][4] = {};

  for (int k0 = 0; k0 < K; k0 += 64) {
    int rb = wave * 32;
#pragma unroll
    for (int j = 0; j < 4; j++) {
      int r = rb + j * 8 + (lane >> 3);
      int ca = (lane & 7) ^ (r & 7);
      gload_lds16(A + (size_t)(m0 + r) * K + k0 + ca * 8, As + (rb + j * 8) * 64);
      gload_lds16(Bt + (size_t)(n0 + r) * K + k0 + ca * 8, Bs + (rb + j * 8) * 64);
    }
    __syncthreads();
#pragma unroll
    for (int ks = 0; ks < 2; ks++) {
      bf16x8 af[4], bfr[4];
#pragma unroll
      for (int mi = 0; mi < 4; mi++) {
        int row = wm * 64 + mi * 16 + c16;
        int ch = (ks * 4 + g) ^ (row & 7);
        af[mi] = *(const bf16x8*)(As + row * 64 + ch * 8);
      }
#pragma unroll
      for (int nj = 0; nj < 4; nj++) {
        int row = wn * 64 + nj * 16 + c16;
        int ch = (ks * 4 + g) ^ (row & 7);
        bfr[nj] = *(const bf16x8*)(Bs + row * 64 + ch * 8);
      }
#pragma unroll
      for (int mi = 0; mi < 4; mi++)
#pragma unroll
        for (int nj = 0; nj < 4; nj++)
          acc[mi][nj] = __builtin_amdgcn_mfma_f32_16x16x32_bf16(
              af[mi], bfr[nj], acc[mi][nj], 0, 0, 0);
    }
    __syncthreads();
  }

  // epilogue. D layout: col = lane&15, row = (lane>>4)*4 + reg
  if (EPI == 0) {
    const float QSC = 0.125f * 1.44269504088896f;  // fold log2(e) for exp2 softmax
    unsigned short* Qb = (unsigned short*)out0;
#pragma unroll
    for (int nj = 0; nj < 4; nj++) {
      int n = n0 + wn * 64 + nj * 16 + c16;
      int t = n / 768, rr = n % 768;
      int h = rr >> 6, d = rr & 63;
      float bv = bias[n];
#pragma unroll
      for (int mi = 0; mi < 4; mi++) {
        int mrow = m0 + wm * 64 + mi * 16 + g * 4;
        int b = mrow >> 11, s = mrow & 2047;
        if (t == 0) {
          size_t base = ((size_t)(b * 12 + h) * 2048 + s) * 64 + d;
#pragma unroll
          for (int rg = 0; rg < 4; rg++)
            Qb[base + (size_t)rg * 64] = f2bf((acc[mi][nj][rg] + bv) * QSC);
        } else if (t == 1) {
          size_t base = ((size_t)(b * 12 + h) * 2048 + s) * 64 + d;
#pragma unroll
          for (int rg = 0; rg < 4; rg++)
            Kb[base + (size_t)rg * 64] = f2bf(acc[mi][nj][rg] + bv);
        } else {
          // V store with key-permutation (4-aligned groups stay contiguous)
          int sp = (s & ~31) + (((s >> 2) & 3) << 3) + (((s >> 4) & 1) << 2);
          u16x4 p;
          p[0] = f2bf(acc[mi][nj][0] + bv);
          p[1] = f2bf(acc[mi][nj][1] + bv);
          p[2] = f2bf(acc[mi][nj][2] + bv);
          p[3] = f2bf(acc[mi][nj][3] + bv);
          *(u16x4*)(Vt + ((size_t)(b * 12 + h) * 64 + d) * 2048 + sp) = p;
        }
      }
    }
  } else {
    float* outp = (float*)out0;
#pragma unroll
    for (int nj = 0; nj < 4; nj++) {
      int n = n0 + wn * 64 + nj * 16 + c16;
      float bv = bias[n];
#pragma unroll
      for (int mi = 0; mi < 4; mi++) {
        int mrow = m0 + wm * 64 + mi * 16 + g * 4;
#pragma unroll
        for (int rg = 0; rg < 4; rg++)
          outp[(size_t)(mrow + rg) * N + n] = acc[mi][nj][rg] + bv;
      }
    }
  }
}

// ---------------- flash attention v10 EXACT (63.2 us, verified 3 runs) --------
// grid 768 x 256 (4 waves, 2 q-subtiles of 16 rows each). XCD-residency swizzle
// (FETCH 104->18.5 MB), in-register P (k-slot permutation matched by permuted
// Vt so PV B-frag is one b128), exp2-no-max softmax, deferred l-reduction.
// R6/R7/R15 all showed this single-buffer 64-key-tile loop is a local optimum:
// dbuf, cross-barrier prefetch, and 2-tile batching each regressed it.
__global__ __launch_bounds__(256, 4) void attn_kernel(
    const unsigned short* __restrict__ Qb,
    const unsigned short* __restrict__ Kb,
    const unsigned short* __restrict__ Vt,
    unsigned short* __restrict__ Ao) {
  __shared__ unsigned short Ks[64 * 64];
  __shared__ unsigned short Vs[64 * 64];
  const int id = blockIdx.x;
  const int xcd = id & 7, slot = id >> 3;
  const int bh = xcd * 6 + (slot % 6);
  const int q0 = (slot / 6) * 128;
  const int tid = threadIdx.x;
  const int wave = tid >> 6, lane = tid & 63;
  const int g = lane >> 4, c16 = lane & 15;
  const int rw = c16 & 7;
  const int rb = wave * 16;

  // staging geometry (kt-invariant): rows sr, sr+8 share the same chunk swizzle
  const int sr = rb + (lane >> 3);
  const int sca = (lane & 7) ^ (sr & 7);
  const unsigned short* kp = Kb + ((size_t)bh * 2048 + sr) * 64 + sca * 8;
  const unsigned short* vp = Vt + ((size_t)bh * 64 + sr) * 2048 + sca * 8;

  // Q fragments: subtile qa rows q0+wave*32+qa*16+c16, k-chunks ks*32+g*8
  bf16x8 qf[2][2];
  {
    const unsigned short* qp =
        Qb + ((size_t)bh * 2048 + q0 + wave * 32 + c16) * 64;
#pragma unroll
    for (int qa = 0; qa < 2; qa++) {
      qf[qa][0] = *(const bf16x8*)(qp + qa * 1024 + g * 8);
      qf[qa][1] = *(const bf16x8*)(qp + qa * 1024 + 32 + g * 8);
    }
  }
  f32x4 acc_o[2][4] = {};
  float l_run[2] = {0.f, 0.f};  // lane-partial until final reduce
  const int alane = (lane & 48) + g * 4;  // src lane base for l shfl

  for (int kt = 0; kt < 32; kt++) {
    // stage K [64 keys][64 d] and V^T [64 d][64 permuted keys], source-swizzled
    gload_lds16(kp, Ks + rb * 64);
    gload_lds16(kp + 8 * 64, Ks + (rb + 8) * 64);
    gload_lds16(vp, Vs + rb * 64);
    gload_lds16(vp + 8 * 2048, Vs + (rb + 8) * 64);
    kp += 64 * 64;
    vp += 64;
    __syncthreads();

    // S^T = K * Q^T ; K-frags shared by both q-subtiles
    f32x4 sacc[2][4] = {};
#pragma unroll
    for (int ks = 0; ks < 2; ks++) {
#pragma unroll
      for (int nf = 0; nf < 4; nf++) {
        int row = nf * 16 + c16;
        int ch = (ks * 4 + g) ^ (row & 7);
        bf16x8 kf = *(const bf16x8*)(Ks + row * 64 + ch * 8);
        sacc[0][nf] =
            __builtin_amdgcn_mfma_f32_16x16x32_bf16(kf, qf[0][ks], sacc[0][nf], 0, 0, 0);
        sacc[1][nf] =
            __builtin_amdgcn_mfma_f32_16x16x32_bf16(kf, qf[1][ks], sacc[1][nf], 0, 0, 0);
      }
    }

    // exp2 softmax (no max), in place; lane-partial row-sum only (reduce later)
#pragma unroll
    for (int qa = 0; qa < 2; qa++) {
      float rs = 0.f;
#pragma unroll
      for (int nf = 0; nf < 4; nf++) {
        sacc[qa][nf][0] = __builtin_amdgcn_exp2f(sacc[qa][nf][0]);
        sacc[qa][nf][1] = __builtin_amdgcn_exp2f(sacc[qa][nf][1]);
        sacc[qa][nf][2] = __builtin_amdgcn_exp2f(sacc[qa][nf][2]);
        sacc[qa][nf][3] = __builtin_amdgcn_exp2f(sacc[qa][nf][3]);
        rs += (sacc[qa][nf][0] + sacc[qa][nf][1]) +
              (sacc[qa][nf][2] + sacc[qa][nf][3]);
      }
      l_run[qa] += rs;
    }

    // O += P * V : A-frag in-register (v8 slot order), B-frag single b128
#pragma unroll
    for (int ks = 0; ks < 2; ks++) {
      union { uint32_t w[4]; bf16x8 v8; } pa0, pa1;
      pa0.w[0] = cvtpk_bf16(sacc[0][2 * ks][0], sacc[0][2 * ks][1]);
      pa0.w[1] = cvtpk_bf16(sacc[0][2 * ks][2], sacc[0][2 * ks][3]);
      pa0.w[2] = cvtpk_bf16(sacc[0][2 * ks + 1][0], sacc[0][2 * ks + 1][1]);
      pa0.w[3] = cvtpk_bf16(sacc[0][2 * ks + 1][2], sacc[0][2 * ks + 1][3]);
      pa1.w[0] = cvtpk_bf16(sacc[1][2 * ks][0], sacc[1][2 * ks][1]);
      pa1.w[1] = cvtpk_bf16(sacc[1][2 * ks][2], sacc[1][2 * ks][3]);
      pa1.w[2] = cvtpk_bf16(sacc[1][2 * ks + 1][0], sacc[1][2 * ks + 1][1]);
      pa1.w[3] = cvtpk_bf16(sacc[1][2 * ks + 1][2], sacc[1][2 * ks + 1][3]);
#pragma unroll
      for (int nf = 0; nf < 4; nf++) {
        int row = nf * 16 + c16;
        int ch = (ks * 4 + g) ^ rw;
        bf16x8 vf = *(const bf16x8*)(&Vs[row * 64 + ch * 8]);
        acc_o[0][nf] =
            __builtin_amdgcn_mfma_f32_16x16x32_bf16(pa0.v8, vf, acc_o[0][nf], 0, 0, 0);
        acc_o[1][nf] =
            __builtin_amdgcn_mfma_f32_16x16x32_bf16(pa1.v8, vf, acc_o[1][nf], 0, 0, 0);
      }
    }
    __syncthreads();
  }

  // final l reduction, redistribute from q=c16 to rows q=g*4+rg, store
  const int b = bh / 12, h = bh % 12;
#pragma unroll
  for (int qa = 0; qa < 2; qa++) {
    float t = l_run[qa];
    t += __shfl_xor(t, 16);
    t += __shfl_xor(t, 32);
    float l_q[4];
#pragma unroll
    for (int rg = 0; rg < 4; rg++)
      l_q[rg] = __shfl(t, alane + rg);
#pragma unroll
    for (int nf = 0; nf < 4; nf++) {
#pragma unroll
      for (int rg = 0; rg < 4; rg++) {
        float v = acc_o[qa][nf][rg] / l_q[rg];
        int srow = q0 + wave * 32 + qa * 16 + g * 4 + rg;
        Ao[((size_t)(b * 2048 + srow)) * 768 + h * 64 + nf * 16 + c16] = f2bf(v);
      }
    }
  }
}

extern "C" void kernel_launch(void* const* d_in, const int* in_sizes, int n_in,
                              void* d_out, int out_size, void* d_ws, size_t ws_size,
                              hipStream_t stream) {
  const float* x      = (const float*)d_in[0];
  const float* w_qkv  = (const float*)d_in[1];
  const float* b_qkv  = (const float*)d_in[2];
  const float* w_proj = (const float*)d_in[3];
  const float* b_proj = (const float*)d_in[4];

  unsigned short* xb  = (unsigned short*)d_ws;      // 6291456 elems
  unsigned short* wqt = xb + 6291456;               // 1769472
  unsigned short* wpt = wqt + 1769472;              // 589824
  unsigned short* Qb  = wpt + 589824;               // 6291456
  unsigned short* Kb  = Qb + 6291456;               // 6291456
  unsigned short* Vt  = Kb + 6291456;               // 6291456
  unsigned short* Ao  = Vt + 6291456;               // 6291456

  prep_kernel<<<6720, 256, 0, stream>>>(x, xb, w_qkv, wqt, w_proj, wpt);

  gemm_kernel<0><<<1152, 256, 0, stream>>>(
      xb, wqt, b_qkv, (void*)Qb, Kb, Vt, 8192, 2304, 768);

  attn_kernel<<<768, 256, 0, stream>>>(Qb, Kb, Vt, Ao);

  gemm_kernel<1><<<384, 256, 0, stream>>>(
      Ao, wpt, b_proj, d_out, nullptr, nullptr, 8192, 768, 768);
}